// Round 1
// 215.245 us; speedup vs baseline: 1.0093x; 1.0093x over previous
//
#include <hip/hip_runtime.h>
#include <math.h>

#define BN_EPS 1e-5f
#define NEG_SLOPE 0.2f

__device__ __forceinline__ float relu_f(float x) { return x > 0.f ? x : 0.f; }
__device__ __forceinline__ float leaky_f(float z) { return z > 0.f ? z : NEG_SLOPE * z; }

// ---------------- conv1 (3->64, 3x3 SAME) fused bias+BN+ReLU+2x2maxpool ----------------
// grid 512 = b(8) x cog(16) x q(4); 256 threads = one pooled position, 4 co
__global__ void conv1_pool(const float* __restrict__ img, const float* __restrict__ w,
                           const float* __restrict__ cb, const float* __restrict__ g,
                           const float* __restrict__ bb, const float* __restrict__ m,
                           const float* __restrict__ vv, float* __restrict__ out)
{
    int blk = blockIdx.x;
    int q = blk & 3, cog = (blk >> 2) & 15, b = blk >> 6;
    int t = threadIdx.x;
    int x = t & 31, y = (q << 3) + (t >> 5);

    float acc[4][4] = {};
#pragma unroll
    for (int ci = 0; ci < 3; ++ci) {
        const float* ib = img + (b * 3 + ci) * 4096;
        float rv[4][4];
#pragma unroll
        for (int r = 0; r < 4; ++r) {
            int yy = 2 * y - 1 + r;
            bool yok = (unsigned)yy < 64u;
            const float* p = ib + yy * 64 + 2 * x;
            float2 c01 = yok ? *(const float2*)p : make_float2(0.f, 0.f);
            rv[r][1] = c01.x;
            rv[r][2] = c01.y;
            rv[r][0] = (yok && x > 0) ? p[-1] : 0.f;
            rv[r][3] = (yok && x < 31) ? p[2] : 0.f;
        }
#pragma unroll
        for (int j = 0; j < 4; ++j) {
            const float* wj = w + ((cog * 4 + j) * 3 + ci) * 9;
#pragma unroll
            for (int ky = 0; ky < 3; ++ky)
#pragma unroll
                for (int kx = 0; kx < 3; ++kx) {
                    float wvv = wj[ky * 3 + kx];
#pragma unroll
                    for (int py = 0; py < 2; ++py)
#pragma unroll
                        for (int px = 0; px < 2; ++px)
                            acc[j][py * 2 + px] += rv[py + ky][px + kx] * wvv;
                }
        }
    }
#pragma unroll
    for (int j = 0; j < 4; ++j) {
        int co = cog * 4 + j;
        float inv = g[co] / sqrtf(vv[co] + BN_EPS);
        float sh = cb[co] * inv + (bb[co] - m[co] * inv);
        float v0 = relu_f(acc[j][0] * inv + sh);
        float v1 = relu_f(acc[j][1] * inv + sh);
        float v2 = relu_f(acc[j][2] * inv + sh);
        float v3 = relu_f(acc[j][3] * inv + sh);
        out[((b * 64 + co) * 32 + y) * 32 + x] = fmaxf(fmaxf(v0, v1), fmaxf(v2, v3));
    }
}

// ---------------- conv2: 64->128, 3x3 SAME, SPLIT-K over ci (4 ways) ----------------
// grid 2048 = b(8) x cog(32) x half(2) x kz(4); kz in LOW bits so the 32 cog-blocks
// sharing an input chunk have blk%8 constant -> same XCD L2.
// 256 threads: x2p=(t&15)*2, y=half*16+(t>>4). Each block reduces 16 input channels,
// writes RAW partial sums (no bias/BN) to its kz plane in [n][128] layout.
__global__ void conv2_split(const float* __restrict__ in, const float* __restrict__ w,
                            float* __restrict__ pacc01, float* __restrict__ pacc23)
{
    int blk = blockIdx.x;
    int kz = blk & 3, half = (blk >> 2) & 1, cog = (blk >> 3) & 31, b = blk >> 8;
    int t = threadIdx.x;
    int x2p = (t & 15) * 2;
    int y = half * 16 + (t >> 4);
    bool xnz = x2p != 0;
    bool xhi = x2p == 30;
    const float* ibase = in + b * 64 * 1024 + kz * 16 * 1024;
    int xb = xnz ? x2p - 1 : 0;

    float acc[4][2] = {};

#pragma unroll 2
    for (int ci = 0; ci < 16; ++ci) {
        const float* cb2 = ibase + ci * 1024;
        float rc[3][4];
#pragma unroll
        for (int r = 0; r < 3; ++r) {
            int yy = y - 1 + r;
            bool yok = (unsigned)yy < 32u;
            const float* p = cb2 + yy * 32 + xb;
            float4 f = yok ? *(const float4*)p : make_float4(0.f, 0.f, 0.f, 0.f);
            rc[r][0] = xnz ? f.x : 0.f;
            rc[r][1] = xnz ? f.y : f.x;
            rc[r][2] = xnz ? f.z : f.y;
            float r3 = xnz ? f.w : f.z;
            rc[r][3] = xhi ? 0.f : r3;
        }
#pragma unroll
        for (int j = 0; j < 4; ++j) {
            const float* wj = w + ((cog * 4 + j) * 64 + kz * 16 + ci) * 9;
#pragma unroll
            for (int ky = 0; ky < 3; ++ky)
#pragma unroll
                for (int kx = 0; kx < 3; ++kx) {
                    float wvv = wj[ky * 3 + kx];
                    acc[j][0] += rc[ky][kx] * wvv;
                    acc[j][1] += rc[ky][kx + 1] * wvv;
                }
        }
    }

    int n0 = b * 1024 + y * 32 + x2p;
    float* pp = (kz & 2 ? pacc23 : pacc01) + (size_t)(kz & 1) * 1048576;
    float4 s0 = {acc[0][0], acc[1][0], acc[2][0], acc[3][0]};
    float4 s1 = {acc[0][1], acc[1][1], acc[2][1], acc[3][1]};
    *(float4*)&pp[(size_t)n0 * 128 + cog * 4] = s0;
    *(float4*)&pp[(size_t)(n0 + 1) * 128 + cog * 4] = s1;
}

// combine 4 kz planes + conv-bias + BN + ReLU -> x0 [n][128]
// grid 1024 x 256: one float4 (4 consecutive co) per thread
__global__ void conv2_combine(const float* __restrict__ pacc01, const float* __restrict__ pacc23,
                              const float* __restrict__ cb, const float* __restrict__ g,
                              const float* __restrict__ bb, const float* __restrict__ m,
                              const float* __restrict__ vv, float* __restrict__ x0)
{
    int idx = blockIdx.x * blockDim.x + threadIdx.x;   // 262144 = 8192 nodes * 32 f4
    int c4 = idx & 31;
    const float4* p01 = (const float4*)pacc01;
    const float4* p23 = (const float4*)pacc23;
    float4 a0 = p01[idx];
    float4 a1 = p01[idx + 262144];
    float4 a2 = p23[idx];
    float4 a3 = p23[idx + 262144];
    float sx = a0.x + a1.x + a2.x + a3.x;
    float sy = a0.y + a1.y + a2.y + a3.y;
    float sz = a0.z + a1.z + a2.z + a3.z;
    float sw = a0.w + a1.w + a2.w + a3.w;

    float4 gg = ((const float4*)g)[c4];
    float4 vvv = ((const float4*)vv)[c4];
    float4 bbb = ((const float4*)bb)[c4];
    float4 mm = ((const float4*)m)[c4];
    float4 cbb = ((const float4*)cb)[c4];
    float ix = gg.x / sqrtf(vvv.x + BN_EPS);
    float iy = gg.y / sqrtf(vvv.y + BN_EPS);
    float iz = gg.z / sqrtf(vvv.z + BN_EPS);
    float iw = gg.w / sqrtf(vvv.w + BN_EPS);
    float shx = cbb.x * ix + (bbb.x - mm.x * ix);
    float shy = cbb.y * iy + (bbb.y - mm.y * iy);
    float shz = cbb.z * iz + (bbb.z - mm.z * iz);
    float shw = cbb.w * iw + (bbb.w - mm.w * iw);

    float4 o = {relu_f(sx * ix + shx), relu_f(sy * iy + shy),
                relu_f(sz * iz + shz), relu_f(sw * iw + shw)};
    ((float4*)x0)[idx] = o;
}

// ---------------- tiled GEMM: 32x64 tile, 128 threads, 4x4 micro ----------------
// grid (M/32, N/64)
template <int K, int N>
__global__ void gemm32(const float* __restrict__ A, const float* __restrict__ B,
                       float* __restrict__ C)
{
    __shared__ float As[16][32];
    __shared__ float Bs[16][64];
    int t = threadIdx.x;
    int m0 = blockIdx.x * 32;
    int n0 = blockIdx.y * 64;
    int tx = t & 15, ty = t >> 4;          // micro: rows ty*4.., cols tx*4..
    int am = t >> 2, akq = (t & 3) * 4;    // A-stage
    float acc[4][4] = {};

    for (int k0 = 0; k0 < K; k0 += 16) {
        float4 av = *(const float4*)&A[(size_t)(m0 + am) * K + k0 + akq];
        float4 bv0 = *(const float4*)&B[(size_t)(k0 + ty) * N + n0 + tx * 4];
        float4 bv1 = *(const float4*)&B[(size_t)(k0 + 8 + ty) * N + n0 + tx * 4];
        __syncthreads();
        As[akq + 0][am] = av.x;
        As[akq + 1][am] = av.y;
        As[akq + 2][am] = av.z;
        As[akq + 3][am] = av.w;
        *(float4*)&Bs[ty][tx * 4] = bv0;
        *(float4*)&Bs[ty + 8][tx * 4] = bv1;
        __syncthreads();
#pragma unroll
        for (int kk = 0; kk < 16; ++kk) {
            float4 a4 = *(const float4*)&As[kk][ty * 4];
            float4 b4 = *(const float4*)&Bs[kk][tx * 4];
            float aa[4] = {a4.x, a4.y, a4.z, a4.w};
            float bb4[4] = {b4.x, b4.y, b4.z, b4.w};
#pragma unroll
            for (int i = 0; i < 4; ++i)
#pragma unroll
                for (int j = 0; j < 4; ++j)
                    acc[i][j] += aa[i] * bb4[j];
        }
    }
#pragma unroll
    for (int i = 0; i < 4; ++i) {
        float4 o = {acc[i][0], acc[i][1], acc[i][2], acc[i][3]};
        *(float4*)&C[(size_t)(m0 + ty * 4 + i) * N + n0 + tx * 4] = o;
    }
}

// ---------------- attention scores for nodes < 1024 (one wave per row) ----------------
__global__ void score_kernel(const float* __restrict__ h, const float* __restrict__ asrc,
                             const float* __restrict__ adst, float* __restrict__ s,
                             float* __restrict__ d, int D, int N)
{
    int gt = blockIdx.x * blockDim.x + threadIdx.x;
    int wave = gt >> 6, lane = gt & 63;
    if (wave >= N) return;
    const float* hp = h + (size_t)wave * D;
    float ss = 0.f, dd = 0.f;
    for (int c = lane; c < D; c += 64) {
        float hv = hp[c];
        ss += hv * asrc[c];
        dd += hv * adst[c];
    }
    for (int off = 32; off; off >>= 1) {
        ss += __shfl_down(ss, off);
        dd += __shfl_down(dd, off);
    }
    if (lane == 0) { s[wave] = ss; d[wave] = dd; }
}

// ---------------- GAT aggregation as split-K GEMM, 32x64 tile, 128 threads ----------------
// C[v,c] = sum_u exp(leaky(s[u]+d[v]) - m[v]) * h[u,c];  m[v] = leaky(smax + d[v])
// grid (32, D/64, KS); 128 threads
template <int D, int KS>
__global__ void gat_agg_gemm(const float* __restrict__ h, const float* __restrict__ s,
                             const float* __restrict__ d, float* __restrict__ pacc,
                             float* __restrict__ pden)
{
    __shared__ float Ss[1024];
    __shared__ float As[16][32];
    __shared__ float Bs[16][64];
    __shared__ float red[2];
    __shared__ float part[16][32];

    const int CH = 1024 / KS;
    int t = threadIdx.x;
    int m0 = blockIdx.x * 32;
    int n0 = blockIdx.y * 64;
    int kz = blockIdx.z;
    int tx = t & 15, ty = t >> 4;
    int ug = t >> 3, vg4 = (t & 7) * 4;   // A-gen: u-row ug, v-cols vg4..+3

    // stage s (8 per thread) + global max
    float4 sa = *(const float4*)&s[t * 8];
    float4 sb = *(const float4*)&s[t * 8 + 4];
    *(float4*)&Ss[t * 8] = sa;
    *(float4*)&Ss[t * 8 + 4] = sb;
    float lm = fmaxf(fmaxf(fmaxf(sa.x, sa.y), fmaxf(sa.z, sa.w)),
                     fmaxf(fmaxf(sb.x, sb.y), fmaxf(sb.z, sb.w)));
#pragma unroll
    for (int off = 1; off < 64; off <<= 1) lm = fmaxf(lm, __shfl_xor(lm, off));
    if ((t & 63) == 0) red[t >> 6] = lm;
    __syncthreads();
    float smax = fmaxf(red[0], red[1]);

    float4 dv = *(const float4*)&d[m0 + vg4];
    float4 mv = {leaky_f(smax + dv.x), leaky_f(smax + dv.y),
                 leaky_f(smax + dv.z), leaky_f(smax + dv.w)};
    float4 dsum = {0.f, 0.f, 0.f, 0.f};
    float acc[4][4] = {};

    for (int k0 = kz * CH; k0 < kz * CH + CH; k0 += 16) {
        float4 bv0 = *(const float4*)&h[(size_t)(k0 + ty) * D + n0 + tx * 4];
        float4 bv1 = *(const float4*)&h[(size_t)(k0 + 8 + ty) * D + n0 + tx * 4];
        float su = Ss[k0 + ug];
        float4 avv;
        avv.x = __expf(leaky_f(su + dv.x) - mv.x);
        avv.y = __expf(leaky_f(su + dv.y) - mv.y);
        avv.z = __expf(leaky_f(su + dv.z) - mv.z);
        avv.w = __expf(leaky_f(su + dv.w) - mv.w);
        dsum.x += avv.x; dsum.y += avv.y; dsum.z += avv.z; dsum.w += avv.w;
        __syncthreads();
        *(float4*)&As[ug][vg4] = avv;
        *(float4*)&Bs[ty][tx * 4] = bv0;
        *(float4*)&Bs[ty + 8][tx * 4] = bv1;
        __syncthreads();
#pragma unroll
        for (int kk = 0; kk < 16; ++kk) {
            float4 a4 = *(const float4*)&As[kk][ty * 4];
            float4 b4 = *(const float4*)&Bs[kk][tx * 4];
            float aa[4] = {a4.x, a4.y, a4.z, a4.w};
            float bb4[4] = {b4.x, b4.y, b4.z, b4.w};
#pragma unroll
            for (int i = 0; i < 4; ++i)
#pragma unroll
                for (int j = 0; j < 4; ++j)
                    acc[i][j] += aa[i] * bb4[j];
        }
    }

    __syncthreads();
    *(float4*)&part[ug][vg4] = dsum;
    __syncthreads();

#pragma unroll
    for (int i = 0; i < 4; ++i) {
        int r = ty * 4 + i;
        float4 o = {acc[i][0], acc[i][1], acc[i][2], acc[i][3]};
        *(float4*)&pacc[((size_t)kz * 1024 + m0 + r) * D + n0 + tx * 4] = o;
    }
    if (t < 32) {
        float den = 0.f;
#pragma unroll
        for (int u = 0; u < 16; ++u) den += part[u][t];
        pden[kz * 1024 + m0 + t] = den;   // redundant across n0-blocks: same value, benign
    }
}

// combine split-K partials: out[v,c] = relu(sum_ks pacc / sum_ks pden + bias)
template <int D, int KS>
__global__ void gat_combine(const float* __restrict__ pacc, const float* __restrict__ pden,
                            const float* __restrict__ bias, float* __restrict__ out)
{
    int idx = blockIdx.x * blockDim.x + threadIdx.x;
    if (idx >= 1024 * D / 4) return;
    int c4 = idx & (D / 4 - 1);
    int v = idx / (D / 4);
    float4 a = {0.f, 0.f, 0.f, 0.f};
    float den = 0.f;
#pragma unroll
    for (int ks = 0; ks < KS; ++ks) {
        float4 p = ((const float4*)pacc)[(size_t)(ks * 1024 + v) * (D / 4) + c4];
        a.x += p.x; a.y += p.y; a.z += p.z; a.w += p.w;
        den += pden[ks * 1024 + v];
    }
    float rd = 1.f / den;
    float4 bz = ((const float4*)bias)[c4];
    float4 o = {relu_f(a.x * rd + bz.x), relu_f(a.y * rd + bz.y),
                relu_f(a.z * rd + bz.z), relu_f(a.w * rd + bz.w)};
    ((float4*)out)[(size_t)v * (D / 4) + c4] = o;
}

// ---------------- self-loop-only rows v in [1024,8192): out = relu(h[v] + bias) ----------------
template <int D>
__global__ void gat_self4(const float* __restrict__ h, const float* __restrict__ bias,
                          float* __restrict__ out)
{
    int idx = blockIdx.x * blockDim.x + threadIdx.x;
    if (idx >= 7168 * D / 4) return;
    int c4 = idx & (D / 4 - 1);
    int n = 1024 + idx / (D / 4);
    float4 v = ((const float4*)h)[(size_t)n * (D / 4) + c4];
    float4 bz = ((const float4*)bias)[c4];
    float4 o = {relu_f(v.x + bz.x), relu_f(v.y + bz.y),
                relu_f(v.z + bz.z), relu_f(v.w + bz.w)};
    ((float4*)out)[(size_t)n * (D / 4) + c4] = o;
}

// ---------------- mean-pool stage 1: 128 blocks, each sums 64 rows ----------------
__global__ void pool_part(const float* __restrict__ x2, float* __restrict__ part)
{
    int b = blockIdx.x >> 4, seg = blockIdx.x & 15, t = threadIdx.x;
    const float* p = x2 + ((size_t)b * 1024 + seg * 64) * 128 + t;
    float acc = 0.f;
#pragma unroll 8
    for (int n = 0; n < 64; ++n) acc += p[(size_t)n * 128];
    part[(b * 16 + seg) * 128 + t] = acc;
}

// ---------------- head: reduce partials + linear + log_softmax ----------------
__global__ void head_kernel(const float* __restrict__ part, const float* __restrict__ ow,
                            const float* __restrict__ ob, float* __restrict__ out)
{
    __shared__ float pooled[128];
    __shared__ float logits[10];
    int b = blockIdx.x, t = threadIdx.x;
    float acc = 0.f;
#pragma unroll
    for (int sgi = 0; sgi < 16; ++sgi) acc += part[(b * 16 + sgi) * 128 + t];
    pooled[t] = acc * (1.f / 1024.f);
    __syncthreads();
    if (t < 10) {
        float l = ob[t];
        for (int c = 0; c < 128; ++c) l += pooled[c] * ow[c * 10 + t];
        logits[t] = l;
    }
    __syncthreads();
    if (t == 0) {
        float mx = logits[0];
        for (int j = 1; j < 10; ++j) mx = fmaxf(mx, logits[j]);
        float sum = 0.f;
        for (int j = 0; j < 10; ++j) sum += expf(logits[j] - mx);
        float lse = mx + logf(sum);
        for (int j = 0; j < 10; ++j) out[b * 10 + j] = logits[j] - lse;
    }
}

extern "C" void kernel_launch(void* const* d_in, const int* in_sizes, int n_in,
                              void* d_out, int out_size, void* d_ws, size_t ws_size,
                              hipStream_t stream)
{
    const float* images = (const float*)d_in[0];
    const float* c1w = (const float*)d_in[1];
    const float* c1b = (const float*)d_in[2];
    const float* bn1g = (const float*)d_in[3];
    const float* bn1b = (const float*)d_in[4];
    const float* bn1m = (const float*)d_in[5];
    const float* bn1v = (const float*)d_in[6];
    const float* c2w = (const float*)d_in[7];
    const float* c2b = (const float*)d_in[8];
    const float* bn2g = (const float*)d_in[9];
    const float* bn2b = (const float*)d_in[10];
    const float* bn2m = (const float*)d_in[11];
    const float* bn2v = (const float*)d_in[12];
    const float* g1w = (const float*)d_in[13];
    const float* g1as = (const float*)d_in[14];
    const float* g1ad = (const float*)d_in[15];
    const float* g1b = (const float*)d_in[16];
    const float* g2w = (const float*)d_in[17];
    const float* g2as = (const float*)d_in[18];
    const float* g2ad = (const float*)d_in[19];
    const float* g2b = (const float*)d_in[20];
    const float* ow = (const float*)d_in[21];
    const float* ob = (const float*)d_in[22];
    float* out = (float*)d_out;

    // ws layout (floats), total ~27.3 MB:
    // [x1 2097152][bufc1 524288][h1 2097152][x0 1048576][h2 1048576][s1,d1,s2,d2]
    // conv2 split-K planes: kz0/1 alias x1 (dead until gat_combine1),
    //                       kz2/3 alias h1 (dead until gemm32-1). bufc1 (live input) untouched.
    // pacc1 (KS=8, 2M fl) aliases x0+h2 (both dead/unwritten during gat1-agg)
    // pacc2 (KS=16, 2M fl) aliases h1 (dead after gat_self1)
    // part/pden1/pden2 alias bufc1 (dead after conv2); x2 aliases x0 (dead after combine1)
    float* ws = (float*)d_ws;
    float* x1    = ws;                   // 2,097,152
    float* bufc1 = ws + 2097152;         //   524,288
    float* h1    = ws + 2621440;         // 2,097,152
    float* x0    = ws + 4718592;         // 1,048,576
    float* h2    = ws + 5767168;         // 1,048,576
    float* s1    = ws + 6815744;         // 1,024
    float* d1    = ws + 6816768;
    float* s2    = ws + 6817792;
    float* d2    = ws + 6818816;
    float* part  = bufc1;                // 16,384
    float* pden1 = bufc1 + 16384;        // 8,192
    float* pden2 = bufc1 + 24576;        // 16,384
    float* pacc1 = x0;                   // 8*1024*256 = 2,097,152 (spans x0+h2)
    float* pacc2 = h1;                   // 16*1024*128 = 2,097,152
    float* x2    = x0;
    float* c2p01 = x1;                   // conv2 split-K planes 0,1 (2*1,048,576)
    float* c2p23 = h1;                   // conv2 split-K planes 2,3 (2*1,048,576)

    conv1_pool<<<512, 256, 0, stream>>>(images, c1w, c1b, bn1g, bn1b, bn1m, bn1v, bufc1);
    conv2_split<<<2048, 256, 0, stream>>>(bufc1, c2w, c2p01, c2p23);
    conv2_combine<<<1024, 256, 0, stream>>>(c2p01, c2p23, c2b, bn2g, bn2b, bn2m, bn2v, x0);

    gemm32<128, 256><<<dim3(256, 4), 128, 0, stream>>>(x0, g1w, h1);
    score_kernel<<<256, 256, 0, stream>>>(h1, g1as, g1ad, s1, d1, 256, 1024);
    gat_agg_gemm<256, 8><<<dim3(32, 4, 8), 128, 0, stream>>>(h1, s1, d1, pacc1, pden1);
    gat_combine<256, 8><<<256, 256, 0, stream>>>(pacc1, pden1, g1b, x1);
    gat_self4<256><<<1792, 256, 0, stream>>>(h1, g1b, x1);

    gemm32<256, 128><<<dim3(256, 2), 128, 0, stream>>>(x1, g2w, h2);
    score_kernel<<<256, 256, 0, stream>>>(h2, g2as, g2ad, s2, d2, 128, 1024);
    gat_agg_gemm<128, 16><<<dim3(32, 2, 16), 128, 0, stream>>>(h2, s2, d2, pacc2, pden2);
    gat_combine<128, 16><<<128, 256, 0, stream>>>(pacc2, pden2, g2b, x2);
    gat_self4<128><<<896, 256, 0, stream>>>(h2, g2b, x2);

    pool_part<<<128, 128, 0, stream>>>(x2, part);
    head_kernel<<<8, 128, 0, stream>>>(part, ow, ob, out);
}